// Round 17
// baseline (1538.340 us; speedup 1.0000x reference)
//
#include <hip/hip_runtime.h>
#include <hip/hip_bf16.h>
#include <cstdint>

#define VOCAB 32000
#define EMB   1024
#define TLEN  2048
#define NB    4
#define MTOT  (NB*TLEN)   // 8192 tokens

typedef __bf16 bf16;
typedef __bf16 bf16x8 __attribute__((ext_vector_type(8)));
typedef float  f32x4  __attribute__((ext_vector_type(4)));

// -------------------- fused {embed || 3 weight transposes} -----------------
__global__ __launch_bounds__(256)
void embed_wt_kernel(const int* __restrict__ idx,
                     const float* __restrict__ tok,
                     const float* __restrict__ pos,
                     bf16* __restrict__ x,
                     const float* __restrict__ Wq,
                     const float* __restrict__ Wk,
                     const float* __restrict__ Wv,
                     bf16* __restrict__ Wqk_t,
                     bf16* __restrict__ Wv_t)
{
    __shared__ bf16 tile[64][65];
    const int q = blockIdx.x, tid = threadIdx.x;
    if (q < 4096) {
        int gid = q * 256 + tid;
        int r   = gid >> 7;
        int c0  = (gid & 127) << 3;
        int t   = r & (TLEN - 1);
        int tk  = idx[r];
        const float4* tp = reinterpret_cast<const float4*>(tok + (long)tk * EMB + c0);
        const float4* pp = reinterpret_cast<const float4*>(pos + (long)t  * EMB + c0);
        float4 a0 = tp[0], a1 = tp[1];
        float4 b0 = pp[0], b1 = pp[1];
        bf16x8 o;
        o[0] = (bf16)(a0.x + b0.x); o[1] = (bf16)(a0.y + b0.y);
        o[2] = (bf16)(a0.z + b0.z); o[3] = (bf16)(a0.w + b0.w);
        o[4] = (bf16)(a1.x + b1.x); o[5] = (bf16)(a1.y + b1.y);
        o[6] = (bf16)(a1.z + b1.z); o[7] = (bf16)(a1.w + b1.w);
        *reinterpret_cast<bf16x8*>(x + (long)r * EMB + c0) = o;
    } else {
        const int q2  = q - 4096;             // [0,768)
        const int sel = q2 >> 8;              // 0=Wq 1=Wk 2=Wv
        const int t   = q2 & 255;
        const float* W = (sel == 0) ? Wq : (sel == 1) ? Wk : Wv;
        bf16* Wt = (sel == 0) ? Wqk_t : (sel == 1) ? (Wqk_t + 1024 * 1024) : Wv_t;
        const int n0 = (t & 15) * 64;
        const int k0 = (t >> 4) * 64;
        int c  = tid & 63, r0 = tid >> 6;
#pragma unroll
        for (int i = 0; i < 16; ++i) {
            int r = r0 + i * 4;
            tile[r][c] = (bf16)W[(long)(k0 + r) * EMB + n0 + c];
        }
        __syncthreads();
        int kc = tid & 63, nr0 = tid >> 6;
#pragma unroll
        for (int i = 0; i < 16; ++i) {
            int nr = nr0 + i * 4;
            Wt[(long)(n0 + nr) * EMB + k0 + kc] = tile[kc][nr];
        }
    }
}

// ------------------------------------------------------------- gll --------
__device__ __forceinline__ void gll16(const void* g, void* l)
{
    __builtin_amdgcn_global_load_lds(
        (const __attribute__((address_space(1))) unsigned int*)g,
        (__attribute__((address_space(3))) unsigned int*)l, 16, 0, 0);
}

// --------------------- shared 256^2 staging (R2-verified, 0 conflicts) -----
__device__ __forceinline__ void stage256s(const bf16* __restrict__ gbase,
                                          int ld, int kt, bf16* lbase, int tid)
{
#pragma unroll
    for (int p = 0; p < 4; ++p) {
        int lin  = p * 512 + tid;
        int row  = lin >> 3;
        int slot = lin & 7;
        int ke   = ((slot ^ (row & 7)) << 3) + kt;
        gll16(gbase + (long)row * ld + ke, lbase + lin * 8);
    }
}

// ----------------- common 256^2 2-phase GEMM body (bf16 out) ---------------
template<int CMODE>
__device__ __forceinline__ void gemm256_body(
    const bf16* __restrict__ A, int lda, long sA,
    const bf16* __restrict__ Bt, int ldb, long sB,
    bf16* __restrict__ C, int ldc, long sC, int K,
    int bx, int by, int zb, bf16* smem, int tid)
{
    bf16* As = smem;                        // [2][256*64]
    bf16* Bs = smem + 32768;

    const int lane = tid & 63, wid = tid >> 6;
    const int wr = wid >> 2, wc = wid & 3;
    const int l15 = lane & 15, hi = lane >> 4, l7 = lane & 7;

    const bf16* Ab = A  + (long)zb * sA + (long)(by * 256) * lda;
    const bf16* Bb = Bt + (long)zb * sB + (long)(bx * 256) * ldb;

    const int Keff = (CMODE == 2) ? ((by + 1) * 256) : K;
    const int NT   = Keff >> 6;

    f32x4 acc[8][4] = {};

    stage256s(Ab, lda, 0, As, tid);
    stage256s(Bb, ldb, 0, Bs, tid);
    __syncthreads();

#pragma unroll 1
    for (int t = 0; t < NT; ++t) {
        const int buf = t & 1;
        if (t + 1 < NT) {
            stage256s(Ab, lda, (t + 1) * 64, As + (buf ^ 1) * 16384, tid);
            stage256s(Bb, ldb, (t + 1) * 64, Bs + (buf ^ 1) * 16384, tid);
        }
        const bf16* Ap = As + buf * 16384 + (wr * 128) * 64;
        const bf16* Bp = Bs + buf * 16384 + (wc * 64) * 64;
#pragma unroll
        for (int ks = 0; ks < 2; ++ks) {
            const int ko = 8 * (((ks << 2) | hi) ^ l7);
            bf16x8 bfr[4];
#pragma unroll
            for (int n = 0; n < 4; ++n)
                bfr[n] = *(const bf16x8*)(Bp + (n * 16 + l15) * 64 + ko);
#pragma unroll
            for (int m = 0; m < 8; ++m) {
                bf16x8 af = *(const bf16x8*)(Ap + (m * 16 + l15) * 64 + ko);
#pragma unroll
                for (int n = 0; n < 4; ++n)
                    acc[m][n] = __builtin_amdgcn_mfma_f32_16x16x32_bf16(
                                    af, bfr[n], acc[m][n], 0, 0, 0);
            }
        }
        __syncthreads();
    }

    bf16* Cb = C + (long)zb * sC;
    const int colb = bx * 256 + wc * 64 + l15;
    const int rowb = by * 256 + wr * 128 + (hi << 2);
#pragma unroll
    for (int m = 0; m < 8; ++m)
#pragma unroll
        for (int n = 0; n < 4; ++n)
#pragma unroll
            for (int r = 0; r < 4; ++r)
                Cb[(long)(rowb + m * 16 + r) * ldc + colb + n * 16] =
                    (bf16)acc[m][n][r];
}

// standalone wrapper (used for qk)
template<int CMODE>
__global__ __launch_bounds__(512)
void gemm256_bt(const bf16* __restrict__ A, int lda, long sA,
                const bf16* __restrict__ Bt, int ldb, long sB,
                bf16* __restrict__ C, int ldc, long sC, int K)
{
    extern __shared__ bf16 smem[];
    gemm256_body<CMODE>(A, lda, sA, Bt, ldb, sB, C, ldc, sC, K,
                        blockIdx.x, blockIdx.y, blockIdx.z, smem, threadIdx.x);
}

// ----------------- fused {v_t GEMM || S lower-tri GEMM} --------------------
__global__ __launch_bounds__(512)
void fused_vt_s(const bf16* __restrict__ Wv_t, const bf16* __restrict__ x,
                bf16* __restrict__ v_t,
                const bf16* __restrict__ qk, bf16* __restrict__ S)
{
    extern __shared__ bf16 smem[];
    const int q = blockIdx.x, tid = threadIdx.x;
    if (q < 128) {
        gemm256_body<0>(Wv_t, EMB, 0, x, EMB, 0, v_t, MTOT, 0, EMB,
                        q & 31, q >> 5, 0, smem, tid);
    } else {
        int q2 = q - 128;                 // [0,144)
        int z = q2 / 36, t = q2 % 36;
        int by = 0, a = 0;
        while (a + by + 1 <= t) { a += by + 1; ++by; }
        int bx = t - a;                   // bx <= by
        gemm256_body<0>(qk, 2048, (long)TLEN * 2048,
                        qk + 1024, 2048, (long)TLEN * 2048,
                        S, TLEN, (long)TLEN * TLEN, EMB, bx, by, z, smem, tid);
    }
}

// ----------------- fused {PV GEMM || Wlm transpose} ------------------------
__global__ __launch_bounds__(512)
void fused_pv_wt(const bf16* __restrict__ P, const bf16* __restrict__ v_t,
                 bf16* __restrict__ att,
                 const float* __restrict__ Wlm, bf16* __restrict__ Wlm_t)
{
    extern __shared__ bf16 smem[];
    const int q = blockIdx.x, tid = threadIdx.x;
    if (q < 128) {
        gemm256_body<2>(P, TLEN, (long)TLEN * TLEN, v_t, MTOT, (long)TLEN,
                        att, EMB, (long)TLEN * EMB, TLEN,
                        q & 3, (q >> 2) & 7, q >> 5, smem, tid);
    } else {
        const int q2 = q - 128;               // [0,2000)
        const int n0 = (q2 % 125) * 256;
        const int k0 = (q2 / 125) * 64;
        bf16 (*tile)[257] = (bf16(*)[257])smem;   // 64 x 257 (+pad)
#pragma unroll
        for (int i = 0; i < 8; ++i) {
            int lin = i * 512 + tid;          // 0..4095
            int r = lin >> 6, c4 = lin & 63;
            float4 v = *(const float4*)(Wlm + (long)(k0 + r) * VOCAB + n0 + c4 * 4);
            tile[r][c4 * 4 + 0] = (bf16)v.x;
            tile[r][c4 * 4 + 1] = (bf16)v.y;
            tile[r][c4 * 4 + 2] = (bf16)v.z;
            tile[r][c4 * 4 + 3] = (bf16)v.w;
        }
        __syncthreads();
#pragma unroll
        for (int i = 0; i < 4; ++i) {
            int lin = i * 512 + tid;          // 0..2047
            int nr = lin >> 3, kc8 = (lin & 7) * 8;
            bf16x8 o;
#pragma unroll
            for (int j = 0; j < 8; ++j) o[j] = tile[kc8 + j][nr];
            *(bf16x8*)(Wlm_t + (long)(n0 + nr) * EMB + k0 + kc8) = o;
        }
    }
}

// ---------------- 256x128-tile logits GEMM, 256 thr, 2 blocks/CU -----------
// Cross-block overlap experiment (m114): 256-thread blocks DO co-schedule
// (R1: 33.8% occ, R6: 35%); 512-thread did not (R11). 4 waves (2M x 2N),
// per-wave 128x64 (same per-thread workload as 256^2/8-wave). BK=32,
// LDS 48 KB static -> 2 blocks/CU if VGPR <= 256. [*][32] b128 swizzle
// (R9-verified): slot s of row r holds k-group s^((r>>1)&3), read at
// hi^((l15>>1)&3). Grid 8000 = 8 xcd x (4 mb x 250 nb); concurrent per-XCD
// footprint 16 nb half-panels = 4 MB = one L2 (R14 lesson).
__device__ __forceinline__ void stageL(const bf16* __restrict__ g, int rows,
                                       int kt, bf16* l, int tid)
{
    const int iters = rows >> 6;              // rows*32/8/256
#pragma unroll
    for (int p = 0; p < 4; ++p) {
        if (p < iters) {
            int lin  = p * 256 + tid;
            int row  = lin >> 2;
            int slot = lin & 3;
            int ke   = ((slot ^ ((row >> 1) & 3)) << 3) + kt;
            gll16(g + (long)row * EMB + ke, l + lin * 8);
        }
    }
}

__global__ __launch_bounds__(256)
void gemm256_logits(const bf16* __restrict__ A, const bf16* __restrict__ Bt,
                    float* __restrict__ C, const float* __restrict__ bias,
                    float2* __restrict__ part)
{
    __shared__ bf16 As[2][256 * 32];          // 32 KB
    __shared__ bf16 Bs[2][128 * 32];          // 16 KB
    __shared__ float pm[2][256];
    __shared__ float ps[2][256];

    const int tid  = threadIdx.x;
    const int lane = tid & 63, wid = tid >> 6;
    const int wr = wid >> 1, wc = wid & 1;
    const int l15 = lane & 15, hi = lane >> 4;

    const int wg = blockIdx.x;
    const int xcd = wg & 7, c = wg >> 3;      // c in [0,1000)
    const int nb = c >> 2;                    // [0,250)
    const int mb = xcd * 4 + (c & 3);         // [0,32)

    const bf16* Ab = A  + (long)(mb * 256) * EMB;
    const bf16* Bb = Bt + (long)(nb * 128) * EMB;

    const long colbase = (long)nb * 128 + wc * 64 + l15;
    float bv[4];
#pragma unroll
    for (int n = 0; n < 4; ++n) bv[n] = bias[colbase + n * 16];

    f32x4 acc[8][4] = {};

    const int ko = 8 * (hi ^ ((l15 >> 1) & 3));
    const bf16* ApR = &As[0][0] + (wr * 128 + l15) * 32 + ko;
    const bf16* BpR = &Bs[0][0] + (wc * 64  + l15) * 32 + ko;

    stageL(Ab, 256, 0, &As[0][0], tid);
    stageL(Bb, 128, 0, &Bs[0][0], tid);
    __syncthreads();

    const int NT = EMB / 32;                  // 32
#pragma unroll 1
    for (int t = 0; t < NT; ++t) {
        const int buf = t & 1;
        if (t + 1 < NT) {
            stageL(Ab, 256, (t + 1) * 32, &As[buf ^ 1][0], tid);
            stageL(Bb, 128, (t + 1) * 32, &Bs[buf ^ 1][0], tid);
        }
        const bf16* Ap = ApR + buf * (256 * 32);
        const bf16* Bp = BpR + buf * (128 * 32);
        bf16x8 bfr[4];
#pragma unroll
        for (int n = 0; n < 4; ++n)
            bfr[n] = *(const bf16x8*)(Bp + (n * 16) * 32);
#pragma unroll
        for (int m = 0; m < 8; ++m) {
            bf16x8 af = *(const bf16x8*)(Ap + (m * 16) * 32);
#pragma unroll
            for (int n = 0; n < 4; ++n)
                acc[m][n] = __builtin_amdgcn_mfma_f32_16x16x32_bf16(
                                af, bfr[n], acc[m][n], 0, 0, 0);
        }
        __syncthreads();
    }

    const long rowbase = (long)mb * 256 + wr * 128;
#pragma unroll
    for (int m = 0; m < 8; ++m) {
#pragma unroll
        for (int r = 0; r < 4; ++r) {
            float v0 = acc[m][0][r] + bv[0];
            float v1 = acc[m][1][r] + bv[1];
            float v2 = acc[m][2][r] + bv[2];
            float v3 = acc[m][3][r] + bv[3];
            long row = rowbase + m * 16 + (hi << 2) + r;
            float* Cp = C + row * (long)VOCAB + colbase;
            __builtin_nontemporal_store(v0, Cp);
            __builtin_nontemporal_store(v1, Cp + 16);
            __builtin_nontemporal_store(v2, Cp + 32);
            __builtin_nontemporal_store(v3, Cp + 48);

            float lm = fmaxf(fmaxf(v0, v1), fmaxf(v2, v3));
#pragma unroll
            for (int o = 1; o < 16; o <<= 1) lm = fmaxf(lm, __shfl_xor(lm, o));
            float sp = __expf(v0 - lm) + __expf(v1 - lm) +
                       __expf(v2 - lm) + __expf(v3 - lm);
#pragma unroll
            for (int o = 1; o < 16; o <<= 1) sp += __shfl_xor(sp, o);
            if (l15 == 0) {
                int rb = wr * 128 + m * 16 + (hi << 2) + r;
                pm[wc][rb] = lm;
                ps[wc][rb] = sp;
            }
        }
    }
    __syncthreads();
    {
        float m0 = pm[0][tid], m1 = pm[1][tid];
        float s0 = ps[0][tid], s1 = ps[1][tid];
        float M = fmaxf(m0, m1);
        float S = s0 * __expf(m0 - M) + s1 * __expf(m1 - M);
        part[(long)nb * MTOT + mb * 256 + tid] = make_float2(M, S);
    }
}

// ------------------------------------------------------ causal softmax -----
__global__ void softmax_causal_kernel(const bf16* __restrict__ S,
                                      bf16* __restrict__ P)
{
    const int r = blockIdx.x;
    const int t = r & (TLEN - 1);
    const int limit = ((t >> 8) + 1) << 8;
    const int tid = threadIdx.x;
    const int lane = tid & 63, wv = tid >> 6;
    const float scale = 0.03125f;
    const int c0 = tid * 8;

    float v[8];
    float m = -1e30f;
    if (c0 < limit) {
        bf16x8 sv = *(const bf16x8*)(S + (long)r * TLEN + c0);
#pragma unroll
        for (int i = 0; i < 8; ++i) {
            float x = (c0 + i <= t) ? (float)sv[i] * scale : -1e30f;
            v[i] = x;
            m = fmaxf(m, x);
        }
    } else {
#pragma unroll
        for (int i = 0; i < 8; ++i) v[i] = -1e30f;
    }
    __shared__ float red[4];
#pragma unroll
    for (int off = 32; off; off >>= 1) m = fmaxf(m, __shfl_xor(m, off));
    if (lane == 0) red[wv] = m;
    __syncthreads();
    m = fmaxf(fmaxf(red[0], red[1]), fmaxf(red[2], red[3]));
    __syncthreads();

    float s = 0.f;
#pragma unroll
    for (int i = 0; i < 8; ++i) { v[i] = __expf(v[i] - m); s += v[i]; }
#pragma unroll
    for (int off = 32; off; off >>= 1) s += __shfl_xor(s, off);
    if (lane == 0) red[wv] = s;
    __syncthreads();
    s = red[0] + red[1] + red[2] + red[3];
    float inv = 1.0f / s;
    if (c0 < limit) {
        bf16x8 o;
#pragma unroll
        for (int i = 0; i < 8; ++i) o[i] = (bf16)(v[i] * inv);
        *(bf16x8*)(P + (long)r * TLEN + c0) = o;
    }
}

// ------------------------------------------------------------- loss --------
// part is [250][8192]: lane-adjacent rows read consecutive float2 -> coalesced
__global__ void loss_combine_kernel(const float2* __restrict__ part,
                                    const float* __restrict__ logits,
                                    const int* __restrict__ tgt,
                                    float* __restrict__ bsum)
{
    const int tid = threadIdx.x;
    const int row = blockIdx.x * 256 + tid;
    const int lane = tid & 63, wv = tid >> 6;
    float M = -1e30f, S = 0.f;
    for (int i = 0; i < 250; ++i) {
        float2 v = part[(long)i * MTOT + row];
        if (v.x <= M) S += v.y * __expf(v.x - M);
        else { S = S * __expf(M - v.x) + v.y; M = v.x; }
    }
    float lse = M + __logf(S);
    float l = lse - logits[(long)row * VOCAB + tgt[row]];
#pragma unroll
    for (int off = 32; off; off >>= 1) l += __shfl_xor(l, off);
    __shared__ float red[4];
    if (lane == 0) red[wv] = l;
    __syncthreads();
    if (tid == 0) bsum[blockIdx.x] = red[0] + red[1] + red[2] + red[3];
}

__global__ void loss_final_kernel(const float* __restrict__ bsum,
                                  float* __restrict__ out)
{
    const int lane = threadIdx.x;
    float s = (lane < 32) ? bsum[lane] : 0.f;
#pragma unroll
    for (int off = 32; off; off >>= 1) s += __shfl_xor(s, off);
    if (lane == 0) out[0] = s * (1.0f / MTOT);
}

// ------------------------------------------------------------- launch ------
extern "C" void kernel_launch(void* const* d_in, const int* in_sizes, int n_in,
                              void* d_out, int out_size, void* d_ws, size_t ws_size,
                              hipStream_t stream)
{
    const int*   idx = (const int*)  d_in[0];
    const int*   tgt = (const int*)  d_in[1];
    const float* tok = (const float*)d_in[2];
    const float* pos = (const float*)d_in[3];
    const float* Wk  = (const float*)d_in[4];
    const float* Wq  = (const float*)d_in[5];
    const float* Wv  = (const float*)d_in[6];
    const float* Wlm = (const float*)d_in[7];
    const float* blm = (const float*)d_in[8];
    float* out = (float*)d_out;

    // ws layout (MB), stream-order-safe:
    //  [  0, 16) x -> att
    //  [ 16, 48) qk -> P -> part [250][8192] f2 (16 MB, logits phase) + bsum
    //  [ 48, 64) v_t
    //  [ 64, 96) S -> Wlm_t [64,126.5)
    //  [ 96,100) Wqk_t  [100,102) Wv_t (dead before Wlm_t write)
    char* ws = (char*)d_ws;
    if (ws_size < (size_t)140 * 1024 * 1024) return;

    bf16*   x     = (bf16*)(ws);
    bf16*   qk    = (bf16*)(ws + (16l << 20));
    bf16*   v_t   = (bf16*)(ws + (48l << 20));
    bf16*   S     = (bf16*)(ws + (64l << 20));
    bf16*   Wqk_t = (bf16*)(ws + (96l << 20));
    bf16*   Wv_t  = (bf16*)(ws + (100l << 20));
    bf16*   att   = (bf16*)(ws);                  // over x
    bf16*   P     = (bf16*)(ws + (16l << 20));    // over qk
    bf16*   Wlm_t = (bf16*)(ws + (64l << 20));    // over S + W*_t
    float2* part  = (float2*)(ws + (16l << 20));  // over qk/P (dead by logits)
    float*  bsum  = (float*)(ws + (33l << 20));

    // 1) fused: embedding || Wq/Wk/Wv transposes
    embed_wt_kernel<<<dim3(4864), 256, 0, stream>>>(
        idx, tok, pos, x, Wq, Wk, Wv, Wqk_t, Wv_t);

    // 2) qk = x @ [Wq|Wk]
    gemm256_bt<0><<<dim3(2048 / 256, MTOT / 256, 1), 512, 131072, stream>>>(
        x, EMB, 0, Wqk_t, EMB, 0, qk, 2048, 0, EMB);

    // 3) fused: v_t = Wv_t @ x^T  ||  S = q k^T (lower-tri tiles)
    fused_vt_s<<<dim3(272), 512, 131072, stream>>>(Wv_t, x, v_t, qk, S);

    // 4) P = softmax(causal(S * C^-0.5))
    softmax_causal_kernel<<<dim3(MTOT), 256, 0, stream>>>(S, P);

    // 5) fused: att = P @ v (causal K-limit)  ||  Wlm transpose -> Wlm_t
    fused_pv_wt<<<dim3(2128), 512, 131072, stream>>>(P, v_t, att, Wlm, Wlm_t);

    // 6) logits = att @ Wlm + blm, fused loss partials (256x128, 2 blk/CU)
    gemm256_logits<<<dim3(8000), 256, 0, stream>>>(att, Wlm_t, out, blm, part);

    // 7) loss
    loss_combine_kernel<<<dim3(32), 256, 0, stream>>>(part, out, tgt, bsum);
    loss_final_kernel<<<dim3(1), 64, 0, stream>>>(bsum, out + (long)MTOT * VOCAB);
}

// Round 18
// 820.630 us; speedup vs baseline: 1.8746x; 1.8746x over previous
//
#include <hip/hip_runtime.h>
#include <hip/hip_bf16.h>
#include <cstdint>

#define VOCAB 32000
#define EMB   1024
#define TLEN  2048
#define NB    4
#define MTOT  (NB*TLEN)   // 8192 tokens

typedef __bf16 bf16;
typedef __bf16 bf16x8 __attribute__((ext_vector_type(8)));
typedef float  f32x4  __attribute__((ext_vector_type(4)));

// -------------------- fused {embed || 3 weight transposes} -----------------
__global__ __launch_bounds__(256)
void embed_wt_kernel(const int* __restrict__ idx,
                     const float* __restrict__ tok,
                     const float* __restrict__ pos,
                     bf16* __restrict__ x,
                     const float* __restrict__ Wq,
                     const float* __restrict__ Wk,
                     const float* __restrict__ Wv,
                     bf16* __restrict__ Wqk_t,
                     bf16* __restrict__ Wv_t)
{
    __shared__ bf16 tile[64][65];
    const int q = blockIdx.x, tid = threadIdx.x;
    if (q < 4096) {
        int gid = q * 256 + tid;
        int r   = gid >> 7;
        int c0  = (gid & 127) << 3;
        int t   = r & (TLEN - 1);
        int tk  = idx[r];
        const float4* tp = reinterpret_cast<const float4*>(tok + (long)tk * EMB + c0);
        const float4* pp = reinterpret_cast<const float4*>(pos + (long)t  * EMB + c0);
        float4 a0 = tp[0], a1 = tp[1];
        float4 b0 = pp[0], b1 = pp[1];
        bf16x8 o;
        o[0] = (bf16)(a0.x + b0.x); o[1] = (bf16)(a0.y + b0.y);
        o[2] = (bf16)(a0.z + b0.z); o[3] = (bf16)(a0.w + b0.w);
        o[4] = (bf16)(a1.x + b1.x); o[5] = (bf16)(a1.y + b1.y);
        o[6] = (bf16)(a1.z + b1.z); o[7] = (bf16)(a1.w + b1.w);
        *reinterpret_cast<bf16x8*>(x + (long)r * EMB + c0) = o;
    } else {
        const int q2  = q - 4096;             // [0,768)
        const int sel = q2 >> 8;              // 0=Wq 1=Wk 2=Wv
        const int t   = q2 & 255;
        const float* W = (sel == 0) ? Wq : (sel == 1) ? Wk : Wv;
        bf16* Wt = (sel == 0) ? Wqk_t : (sel == 1) ? (Wqk_t + 1024 * 1024) : Wv_t;
        const int n0 = (t & 15) * 64;
        const int k0 = (t >> 4) * 64;
        int c  = tid & 63, r0 = tid >> 6;
#pragma unroll
        for (int i = 0; i < 16; ++i) {
            int r = r0 + i * 4;
            tile[r][c] = (bf16)W[(long)(k0 + r) * EMB + n0 + c];
        }
        __syncthreads();
        int kc = tid & 63, nr0 = tid >> 6;
#pragma unroll
        for (int i = 0; i < 16; ++i) {
            int nr = nr0 + i * 4;
            Wt[(long)(n0 + nr) * EMB + k0 + kc] = tile[kc][nr];
        }
    }
}

// ------------------------------------------------------------- gll --------
__device__ __forceinline__ void gll16(const void* g, void* l)
{
    __builtin_amdgcn_global_load_lds(
        (const __attribute__((address_space(1))) unsigned int*)g,
        (__attribute__((address_space(3))) unsigned int*)l, 16, 0, 0);
}

// --------------------- shared 256^2 staging (R2-verified, 0 conflicts) -----
__device__ __forceinline__ void stage256s(const bf16* __restrict__ gbase,
                                          int ld, int kt, bf16* lbase, int tid)
{
#pragma unroll
    for (int p = 0; p < 4; ++p) {
        int lin  = p * 512 + tid;
        int row  = lin >> 3;
        int slot = lin & 7;
        int ke   = ((slot ^ (row & 7)) << 3) + kt;
        gll16(gbase + (long)row * ld + ke, lbase + lin * 8);
    }
}

// ----------------- common 256^2 2-phase GEMM body (bf16 out) ---------------
template<int CMODE>
__device__ __forceinline__ void gemm256_body(
    const bf16* __restrict__ A, int lda, long sA,
    const bf16* __restrict__ Bt, int ldb, long sB,
    bf16* __restrict__ C, int ldc, long sC, int K,
    int bx, int by, int zb, bf16* smem, int tid)
{
    bf16* As = smem;                        // [2][256*64]
    bf16* Bs = smem + 32768;

    const int lane = tid & 63, wid = tid >> 6;
    const int wr = wid >> 2, wc = wid & 3;
    const int l15 = lane & 15, hi = lane >> 4, l7 = lane & 7;

    const bf16* Ab = A  + (long)zb * sA + (long)(by * 256) * lda;
    const bf16* Bb = Bt + (long)zb * sB + (long)(bx * 256) * ldb;

    const int Keff = (CMODE == 2) ? ((by + 1) * 256) : K;
    const int NT   = Keff >> 6;

    f32x4 acc[8][4] = {};

    stage256s(Ab, lda, 0, As, tid);
    stage256s(Bb, ldb, 0, Bs, tid);
    __syncthreads();

#pragma unroll 1
    for (int t = 0; t < NT; ++t) {
        const int buf = t & 1;
        if (t + 1 < NT) {
            stage256s(Ab, lda, (t + 1) * 64, As + (buf ^ 1) * 16384, tid);
            stage256s(Bb, ldb, (t + 1) * 64, Bs + (buf ^ 1) * 16384, tid);
        }
        const bf16* Ap = As + buf * 16384 + (wr * 128) * 64;
        const bf16* Bp = Bs + buf * 16384 + (wc * 64) * 64;
#pragma unroll
        for (int ks = 0; ks < 2; ++ks) {
            const int ko = 8 * (((ks << 2) | hi) ^ l7);
            bf16x8 bfr[4];
#pragma unroll
            for (int n = 0; n < 4; ++n)
                bfr[n] = *(const bf16x8*)(Bp + (n * 16 + l15) * 64 + ko);
#pragma unroll
            for (int m = 0; m < 8; ++m) {
                bf16x8 af = *(const bf16x8*)(Ap + (m * 16 + l15) * 64 + ko);
#pragma unroll
                for (int n = 0; n < 4; ++n)
                    acc[m][n] = __builtin_amdgcn_mfma_f32_16x16x32_bf16(
                                    af, bfr[n], acc[m][n], 0, 0, 0);
            }
        }
        __syncthreads();
    }

    bf16* Cb = C + (long)zb * sC;
    const int colb = bx * 256 + wc * 64 + l15;
    const int rowb = by * 256 + wr * 128 + (hi << 2);
#pragma unroll
    for (int m = 0; m < 8; ++m)
#pragma unroll
        for (int n = 0; n < 4; ++n)
#pragma unroll
            for (int r = 0; r < 4; ++r)
                Cb[(long)(rowb + m * 16 + r) * ldc + colb + n * 16] =
                    (bf16)acc[m][n][r];
}

// standalone wrapper (used for qk)
template<int CMODE>
__global__ __launch_bounds__(512)
void gemm256_bt(const bf16* __restrict__ A, int lda, long sA,
                const bf16* __restrict__ Bt, int ldb, long sB,
                bf16* __restrict__ C, int ldc, long sC, int K)
{
    extern __shared__ bf16 smem[];
    gemm256_body<CMODE>(A, lda, sA, Bt, ldb, sB, C, ldc, sC, K,
                        blockIdx.x, blockIdx.y, blockIdx.z, smem, threadIdx.x);
}

// ----------------- fused {v_t GEMM || S lower-tri GEMM} --------------------
__global__ __launch_bounds__(512)
void fused_vt_s(const bf16* __restrict__ Wv_t, const bf16* __restrict__ x,
                bf16* __restrict__ v_t,
                const bf16* __restrict__ qk, bf16* __restrict__ S)
{
    extern __shared__ bf16 smem[];
    const int q = blockIdx.x, tid = threadIdx.x;
    if (q < 128) {
        gemm256_body<0>(Wv_t, EMB, 0, x, EMB, 0, v_t, MTOT, 0, EMB,
                        q & 31, q >> 5, 0, smem, tid);
    } else {
        int q2 = q - 128;                 // [0,144)
        int z = q2 / 36, t = q2 % 36;
        int by = 0, a = 0;
        while (a + by + 1 <= t) { a += by + 1; ++by; }
        int bx = t - a;                   // bx <= by
        gemm256_body<0>(qk, 2048, (long)TLEN * 2048,
                        qk + 1024, 2048, (long)TLEN * 2048,
                        S, TLEN, (long)TLEN * TLEN, EMB, bx, by, z, smem, tid);
    }
}

// ----------------- fused {PV GEMM || Wlm transpose} ------------------------
__global__ __launch_bounds__(512)
void fused_pv_wt(const bf16* __restrict__ P, const bf16* __restrict__ v_t,
                 bf16* __restrict__ att,
                 const float* __restrict__ Wlm, bf16* __restrict__ Wlm_t)
{
    extern __shared__ bf16 smem[];
    const int q = blockIdx.x, tid = threadIdx.x;
    if (q < 128) {
        gemm256_body<2>(P, TLEN, (long)TLEN * TLEN, v_t, MTOT, (long)TLEN,
                        att, EMB, (long)TLEN * EMB, TLEN,
                        q & 3, (q >> 2) & 7, q >> 5, smem, tid);
    } else {
        const int q2 = q - 128;               // [0,2000)
        const int n0 = (q2 % 125) * 256;
        const int k0 = (q2 / 125) * 64;
        bf16 (*tile)[257] = (bf16(*)[257])smem;   // 64 x 257 (+pad)
#pragma unroll
        for (int i = 0; i < 8; ++i) {
            int lin = i * 512 + tid;          // 0..4095
            int r = lin >> 6, c4 = lin & 63;
            float4 v = *(const float4*)(Wlm + (long)(k0 + r) * VOCAB + n0 + c4 * 4);
            tile[r][c4 * 4 + 0] = (bf16)v.x;
            tile[r][c4 * 4 + 1] = (bf16)v.y;
            tile[r][c4 * 4 + 2] = (bf16)v.z;
            tile[r][c4 * 4 + 3] = (bf16)v.w;
        }
        __syncthreads();
#pragma unroll
        for (int i = 0; i < 4; ++i) {
            int lin = i * 512 + tid;          // 0..2047
            int nr = lin >> 3, kc8 = (lin & 7) * 8;
            bf16x8 o;
#pragma unroll
            for (int j = 0; j < 8; ++j) o[j] = tile[kc8 + j][nr];
            *(bf16x8*)(Wlm_t + (long)(n0 + nr) * EMB + k0 + kc8) = o;
        }
    }
}

// ---------------------------------------------- 256^2 2-phase logits GEMM --
// R13/R16-measured best (~645 us, FETCH 388 MB, 0 conflicts):
// R2 loop + NT stores; part layout [nb][row].
__global__ __launch_bounds__(512)
void gemm256_logits(const bf16* __restrict__ A, const bf16* __restrict__ Bt,
                    float* __restrict__ C, const float* __restrict__ bias,
                    float2* __restrict__ part)
{
    extern __shared__ bf16 smem[];
    bf16* As = smem;
    bf16* Bs = smem + 32768;

    const int tid  = threadIdx.x;
    const int lane = tid & 63, wid = tid >> 6;
    const int wr = wid >> 2, wc = wid & 3;
    const int l15 = lane & 15, hi = lane >> 4, l7 = lane & 7;

    // bijective XCD swizzle: concurrent blocks per XCD span only 8 nb
    // panels (4 MB = one L2) -- do NOT change this mapping (R14 lesson).
    const int wg = blockIdx.x;
    const int xcd = wg & 7, c = wg >> 3;
    const int nb = c >> 2;                    // [0,125)
    const int mb = xcd * 4 + (c & 3);         // [0,32)

    const bf16* Ab = A  + (long)(mb * 256) * EMB;
    const bf16* Bb = Bt + (long)(nb * 256) * EMB;

    // bias hoisted off the epilogue critical path
    const long colbase = (long)nb * 256 + wc * 64 + l15;
    float bv[4];
#pragma unroll
    for (int n = 0; n < 4; ++n) bv[n] = bias[colbase + n * 16];

    f32x4 acc[8][4] = {};

    stage256s(Ab, EMB, 0, As, tid);
    stage256s(Bb, EMB, 0, Bs, tid);
    __syncthreads();

    const int NT = EMB / 64;
#pragma unroll 1
    for (int t = 0; t < NT; ++t) {
        const int buf = t & 1;
        if (t + 1 < NT) {
            stage256s(Ab, EMB, (t + 1) * 64, As + (buf ^ 1) * 16384, tid);
            stage256s(Bb, EMB, (t + 1) * 64, Bs + (buf ^ 1) * 16384, tid);
        }
        const bf16* Ap = As + buf * 16384 + (wr * 128) * 64;
        const bf16* Bp = Bs + buf * 16384 + (wc * 64) * 64;
#pragma unroll
        for (int ks = 0; ks < 2; ++ks) {
            const int ko = 8 * (((ks << 2) | hi) ^ l7);
            bf16x8 bfr[4];
#pragma unroll
            for (int n = 0; n < 4; ++n)
                bfr[n] = *(const bf16x8*)(Bp + (n * 16 + l15) * 64 + ko);
#pragma unroll
            for (int m = 0; m < 8; ++m) {
                bf16x8 af = *(const bf16x8*)(Ap + (m * 16 + l15) * 64 + ko);
#pragma unroll
                for (int n = 0; n < 4; ++n)
                    acc[m][n] = __builtin_amdgcn_mfma_f32_16x16x32_bf16(
                                    af, bfr[n], acc[m][n], 0, 0, 0);
            }
        }
        __syncthreads();
    }

    float* pm = (float*)smem;                 // [4][256]
    float* ps = pm + 1024;                    // [4][256]

    const long rowbase = (long)mb * 256 + wr * 128;
#pragma unroll
    for (int m = 0; m < 8; ++m) {
#pragma unroll
        for (int r = 0; r < 4; ++r) {
            float v0 = acc[m][0][r] + bv[0];
            float v1 = acc[m][1][r] + bv[1];
            float v2 = acc[m][2][r] + bv[2];
            float v3 = acc[m][3][r] + bv[3];
            long row = rowbase + m * 16 + (hi << 2) + r;
            float* Cp = C + row * (long)VOCAB + colbase;
            __builtin_nontemporal_store(v0, Cp);
            __builtin_nontemporal_store(v1, Cp + 16);
            __builtin_nontemporal_store(v2, Cp + 32);
            __builtin_nontemporal_store(v3, Cp + 48);

            float lm = fmaxf(fmaxf(v0, v1), fmaxf(v2, v3));
#pragma unroll
            for (int o = 1; o < 16; o <<= 1) lm = fmaxf(lm, __shfl_xor(lm, o));
            float sp = __expf(v0 - lm) + __expf(v1 - lm) +
                       __expf(v2 - lm) + __expf(v3 - lm);
#pragma unroll
            for (int o = 1; o < 16; o <<= 1) sp += __shfl_xor(sp, o);
            if (l15 == 0) {
                int rb = wr * 128 + m * 16 + (hi << 2) + r;
                pm[wc * 256 + rb] = lm;
                ps[wc * 256 + rb] = sp;
            }
        }
    }
    __syncthreads();
    if (tid < 256) {
        float m0 = pm[tid], m1 = pm[256 + tid], m2 = pm[512 + tid], m3 = pm[768 + tid];
        float M = fmaxf(fmaxf(m0, m1), fmaxf(m2, m3));
        float S = ps[tid] * __expf(m0 - M) + ps[256 + tid] * __expf(m1 - M) +
                  ps[512 + tid] * __expf(m2 - M) + ps[768 + tid] * __expf(m3 - M);
        // [nb][row] layout: 256 consecutive float2 per block -> coalesced
        part[(long)nb * MTOT + mb * 256 + tid] = make_float2(M, S);
    }
}

// ------------------------------------------------------ causal softmax -----
__global__ void softmax_causal_kernel(const bf16* __restrict__ S,
                                      bf16* __restrict__ P)
{
    const int r = blockIdx.x;
    const int t = r & (TLEN - 1);
    const int limit = ((t >> 8) + 1) << 8;
    const int tid = threadIdx.x;
    const int lane = tid & 63, wv = tid >> 6;
    const float scale = 0.03125f;
    const int c0 = tid * 8;

    float v[8];
    float m = -1e30f;
    if (c0 < limit) {
        bf16x8 sv = *(const bf16x8*)(S + (long)r * TLEN + c0);
#pragma unroll
        for (int i = 0; i < 8; ++i) {
            float x = (c0 + i <= t) ? (float)sv[i] * scale : -1e30f;
            v[i] = x;
            m = fmaxf(m, x);
        }
    } else {
#pragma unroll
        for (int i = 0; i < 8; ++i) v[i] = -1e30f;
    }
    __shared__ float red[4];
#pragma unroll
    for (int off = 32; off; off >>= 1) m = fmaxf(m, __shfl_xor(m, off));
    if (lane == 0) red[wv] = m;
    __syncthreads();
    m = fmaxf(fmaxf(red[0], red[1]), fmaxf(red[2], red[3]));
    __syncthreads();

    float s = 0.f;
#pragma unroll
    for (int i = 0; i < 8; ++i) { v[i] = __expf(v[i] - m); s += v[i]; }
#pragma unroll
    for (int off = 32; off; off >>= 1) s += __shfl_xor(s, off);
    if (lane == 0) red[wv] = s;
    __syncthreads();
    s = red[0] + red[1] + red[2] + red[3];
    float inv = 1.0f / s;
    if (c0 < limit) {
        bf16x8 o;
#pragma unroll
        for (int i = 0; i < 8; ++i) o[i] = (bf16)(v[i] * inv);
        *(bf16x8*)(P + (long)r * TLEN + c0) = o;
    }
}

// ------------------------------------------------------------- loss --------
// part is [125][8192]: lane-adjacent rows read consecutive float2 -> coalesced
__global__ void loss_combine_kernel(const float2* __restrict__ part,
                                    const float* __restrict__ logits,
                                    const int* __restrict__ tgt,
                                    float* __restrict__ bsum)
{
    const int tid = threadIdx.x;
    const int row = blockIdx.x * 256 + tid;
    const int lane = tid & 63, wv = tid >> 6;
    float M = -1e30f, S = 0.f;
    for (int i = 0; i < 125; ++i) {
        float2 v = part[(long)i * MTOT + row];
        if (v.x <= M) S += v.y * __expf(v.x - M);
        else { S = S * __expf(M - v.x) + v.y; M = v.x; }
    }
    float lse = M + __logf(S);
    float l = lse - logits[(long)row * VOCAB + tgt[row]];
#pragma unroll
    for (int off = 32; off; off >>= 1) l += __shfl_xor(l, off);
    __shared__ float red[4];
    if (lane == 0) red[wv] = l;
    __syncthreads();
    if (tid == 0) bsum[blockIdx.x] = red[0] + red[1] + red[2] + red[3];
}

__global__ void loss_final_kernel(const float* __restrict__ bsum,
                                  float* __restrict__ out)
{
    const int lane = threadIdx.x;
    float s = (lane < 32) ? bsum[lane] : 0.f;
#pragma unroll
    for (int off = 32; off; off >>= 1) s += __shfl_xor(s, off);
    if (lane == 0) out[0] = s * (1.0f / MTOT);
}

// ------------------------------------------------------------- launch ------
extern "C" void kernel_launch(void* const* d_in, const int* in_sizes, int n_in,
                              void* d_out, int out_size, void* d_ws, size_t ws_size,
                              hipStream_t stream)
{
    const int*   idx = (const int*)  d_in[0];
    const int*   tgt = (const int*)  d_in[1];
    const float* tok = (const float*)d_in[2];
    const float* pos = (const float*)d_in[3];
    const float* Wk  = (const float*)d_in[4];
    const float* Wq  = (const float*)d_in[5];
    const float* Wv  = (const float*)d_in[6];
    const float* Wlm = (const float*)d_in[7];
    const float* blm = (const float*)d_in[8];
    float* out = (float*)d_out;

    char* ws = (char*)d_ws;
    if (ws_size < (size_t)140 * 1024 * 1024) return;

    bf16*   x     = (bf16*)(ws);
    bf16*   qk    = (bf16*)(ws + (16l << 20));
    bf16*   v_t   = (bf16*)(ws + (48l << 20));
    bf16*   S     = (bf16*)(ws + (64l << 20));
    bf16*   Wqk_t = (bf16*)(ws + (96l << 20));
    bf16*   Wv_t  = (bf16*)(ws + (100l << 20));
    bf16*   att   = (bf16*)(ws);                  // over x
    bf16*   P     = (bf16*)(ws + (16l << 20));    // over qk
    bf16*   Wlm_t = (bf16*)(ws + (64l << 20));    // over S + W*_t
    float2* part  = (float2*)(ws + (127l << 20));
    float*  bsum  = (float*)(ws + (135l << 20));

    // 1) fused: embedding || Wq/Wk/Wv transposes
    embed_wt_kernel<<<dim3(4864), 256, 0, stream>>>(
        idx, tok, pos, x, Wq, Wk, Wv, Wqk_t, Wv_t);

    // 2) qk = x @ [Wq|Wk]
    gemm256_bt<0><<<dim3(2048 / 256, MTOT / 256, 1), 512, 131072, stream>>>(
        x, EMB, 0, Wqk_t, EMB, 0, qk, 2048, 0, EMB);

    // 3) fused: v_t = Wv_t @ x^T  ||  S = q k^T (lower-tri tiles)
    fused_vt_s<<<dim3(272), 512, 131072, stream>>>(Wv_t, x, v_t, qk, S);

    // 4) P = softmax(causal(S * C^-0.5))
    softmax_causal_kernel<<<dim3(MTOT), 256, 0, stream>>>(S, P);

    // 5) fused: att = P @ v (causal K-limit)  ||  Wlm transpose -> Wlm_t
    fused_pv_wt<<<dim3(2128), 512, 131072, stream>>>(P, v_t, att, Wlm, Wlm_t);

    // 6) logits = att @ Wlm + blm, fused loss partials
    gemm256_logits<<<dim3(4000), 512, 131072, stream>>>(att, Wlm_t, out, blm, part);

    // 7) loss
    loss_combine_kernel<<<dim3(32), 256, 0, stream>>>(part, out, tgt, bsum);
    loss_final_kernel<<<dim3(1), 64, 0, stream>>>(bsum, out + (long)MTOT * VOCAB);
}